// Round 6
// baseline (423.405 us; speedup 1.0000x reference)
//
#include <hip/hip_runtime.h>
#include <math.h>

#define DF 768      // feature dim
#define NN 64       // nodes
#define DN 832      // batch row stride (D + N)
#define HB 49152    // halves per batch item in h buffers (768*64)
#define NEG_SLOPE 0.2f

typedef _Float16 f16;
typedef __attribute__((ext_vector_type(4))) _Float16 f16x4;
typedef __attribute__((ext_vector_type(8))) _Float16 f16x8;
typedef __attribute__((ext_vector_type(4))) float f32x4;

__device__ __forceinline__ float tanh_fast(float x) {
  return 1.0f - 2.0f / (__expf(2.0f * x) + 1.0f);
}

// ---------- prep: transpose w (768x768 fp32) -> wT[o][k] f16 ----------
__global__ void prep_wT(const float* __restrict__ w, f16* __restrict__ wT) {
  __shared__ float tile[32][33];
  int bx = blockIdx.x % 24;   // o tile
  int by = blockIdx.x / 24;   // k tile
  int tx = threadIdx.x & 31;
  int ty = threadIdx.x >> 5;  // 0..7
#pragma unroll
  for (int rr = 0; rr < 4; ++rr)
    tile[ty + rr * 8][tx] = w[(size_t)(by * 32 + ty + rr * 8) * DF + bx * 32 + tx];
  __syncthreads();
#pragma unroll
  for (int rr = 0; rr < 4; ++rr)
    wT[(size_t)(bx * 32 + ty + rr * 8) * DF + by * 32 + tx] = (f16)tile[tx][ty + rr * 8];
}

// ---------- prep: mlp_w fp32 -> f16 ----------
__global__ void prep_mlp(const float* __restrict__ mw, f16* __restrict__ mwh) {
  int i = blockIdx.x * 256 + threadIdx.x;
  mwh[i] = (f16)mw[i];
}

// ---------- hp = h @ w : M=32768, N=768, K=768 tiled GEMM ----------
// 128x128 tile, BK=64, 256 thr (4 waves as 2x2 of 64x64).
// A source: layer1 = batch fp32 (row-major, stride DN); layer2 = h1 f16 [gm][o].
// B source: wT[o][k] f16. Output: hpT[b][o][m] f16 (m contiguous) for attn kernels.
__global__ __launch_bounds__(256) void gemm_hp(
    const float* __restrict__ batch,
    const f16* __restrict__ hIn,
    const f16* __restrict__ wT,
    f16* __restrict__ hpT,
    int is_l1)
{
  __shared__ __align__(16) f16 At[128 * 72];   // 18432 B, pad 8 -> conflict-free frags
  __shared__ __align__(16) f16 Bt[128 * 72];
  const int tid  = threadIdx.x;
  const int lane = tid & 63;
  const int wv   = tid >> 6;     // 0..3
  const int l16  = lane & 15;
  const int quad = lane >> 4;
  const int bm   = blockIdx.x;   // 0..255 (M tiles)
  const int bn   = blockIdx.y;   // 0..5   (N tiles)
  const int m0w  = (wv & 1) * 64;
  const int n0w  = (wv >> 1) * 64;

  f32x4 acc[4][4];
#pragma unroll
  for (int rt = 0; rt < 4; ++rt)
#pragma unroll
    for (int ct = 0; ct < 4; ++ct)
      acc[rt][ct] = (f32x4){0.f, 0.f, 0.f, 0.f};

  for (int kt = 0; kt < 12; ++kt) {
    const int k0 = kt * 64;
    // ---- stage A (128 rows x 64 k) ----
    if (is_l1) {
      int r  = tid >> 4;           // 0..15
      int c4 = (tid & 15) * 4;     // 0..60
#pragma unroll
      for (int p = 0; p < 8; ++p) {
        int rr = p * 16 + r;
        int gm = bm * 128 + rr;
        const float* ap = batch + (size_t)(gm >> 6) * (NN * DN) + (size_t)(gm & 63) * DN + k0 + c4;
        float4 v = *(const float4*)ap;
        *(f16x4*)&At[rr * 72 + c4] = (f16x4){(f16)v.x, (f16)v.y, (f16)v.z, (f16)v.w};
      }
    } else {
      int r  = tid >> 3;           // 0..31
      int c8 = (tid & 7) * 8;      // 0..56
#pragma unroll
      for (int p = 0; p < 4; ++p) {
        int rr = p * 32 + r;
        int gm = bm * 128 + rr;
        *(f16x8*)&At[rr * 72 + c8] = *(const f16x8*)&hIn[(size_t)gm * DF + k0 + c8];
      }
    }
    // ---- stage B (128 cols x 64 k) ----
    {
      int r  = tid >> 3;
      int c8 = (tid & 7) * 8;
#pragma unroll
      for (int p = 0; p < 4; ++p) {
        int rr = p * 32 + r;
        *(f16x8*)&Bt[rr * 72 + c8] = *(const f16x8*)&wT[(size_t)(bn * 128 + rr) * DF + k0 + c8];
      }
    }
    __syncthreads();
#pragma unroll
    for (int ks = 0; ks < 2; ++ks) {
      f16x8 af[4], bf[4];
#pragma unroll
      for (int rt = 0; rt < 4; ++rt)
        af[rt] = *(const f16x8*)&At[(m0w + rt * 16 + l16) * 72 + ks * 32 + quad * 8];
#pragma unroll
      for (int ct = 0; ct < 4; ++ct)
        bf[ct] = *(const f16x8*)&Bt[(n0w + ct * 16 + l16) * 72 + ks * 32 + quad * 8];
#pragma unroll
      for (int rt = 0; rt < 4; ++rt)
#pragma unroll
        for (int ct = 0; ct < 4; ++ct)
          acc[rt][ct] = __builtin_amdgcn_mfma_f32_16x16x32_f16(af[rt], bf[ct], acc[rt][ct], 0, 0, 0);
    }
    __syncthreads();
  }
  // ---- epilogue: hpT[b][o][m], 4 consecutive m per frag -> f16x4 store ----
#pragma unroll
  for (int rt = 0; rt < 4; ++rt)
#pragma unroll
    for (int ct = 0; ct < 4; ++ct) {
      int mloc = m0w + rt * 16 + quad * 4;
      int gm = bm * 128 + mloc;
      int b = gm >> 6, mm = gm & 63;
      int o = bn * 128 + n0w + ct * 16 + l16;
      f16x4 hv = {(f16)acc[rt][ct][0], (f16)acc[rt][ct][1],
                  (f16)acc[rt][ct][2], (f16)acc[rt][ct][3]};
      *(f16x4*)&hpT[(size_t)b * HB + (size_t)o * 64 + mm] = hv;
    }
}

// ---------- attention layer 1: full softmax + h1 = attn @ hp + bias ----------
// One WG (512 thr, 8 waves) per batch item. hp staged in XOR-swizzled LDS:
// elem (o,m) at Shp[o*64 + ((m>>3 ^ (o&7))<<3 | (m&7))] -> conflict-free for
// staging writes, tanh scalar reads, and GEMM2 B-fragment f16x8 reads.
__global__ __launch_bounds__(512) void attn_l1(
    const float* __restrict__ batch,
    const f16* __restrict__ hpT,      // [b][o][m]
    const float* __restrict__ a_src,
    const float* __restrict__ a_dst,
    const float* __restrict__ gat_bias,
    f16* __restrict__ h1)             // [b][m][o] row-major
{
  __shared__ __align__(16) f16 Shp[DF * 64];    // 98304 B
  __shared__ __align__(16) f16 attnL[NN * 72];  // 9216 B
  __shared__ float asrcL[DF], adstL[DF], biasL[DF];
  __shared__ float redS[8 * NN], redD[8 * NN];
  __shared__ float srcv[NN], dstv[NN];
  __shared__ unsigned long long maskRow[NN];

  const int tid  = threadIdx.x;
  const int lane = tid & 63;
  const int wv   = tid >> 6;    // 0..7
  const int l16  = lane & 15;
  const int quad = lane >> 4;
  const int b    = blockIdx.x;
  const float* bb = batch + (size_t)b * (NN * DN);
  const f16* hp = hpT + (size_t)b * HB;

  for (int i = tid; i < DF; i += 512) {
    asrcL[i] = a_src[i];
    adstL[i] = a_dst[i];
    biasL[i] = gat_bias[i];
  }
  // stage hp -> Shp (swizzled)
  for (int s = tid; s < DF * 8; s += 512) {
    int o = s >> 3, m8 = s & 7;
    f16x8 v = *(const f16x8*)&hp[(size_t)o * 64 + m8 * 8];
    *(f16x8*)&Shp[o * 64 + ((m8 ^ (o & 7)) << 3)] = v;
  }
  // adjacency masks: wave wv rows 8*wv..8*wv+7
#pragma unroll
  for (int r = 0; r < 8; ++r) {
    int n = wv * 8 + r;
    float av = bb[n * DN + DF + lane];
    unsigned long long m = __ballot(av != 0.0f);
    if (lane == 0) maskRow[n] = m | (1ULL << n);
  }
  __syncthreads();

  // tanh dots: wave wv covers o in [wv*96, wv*96+96), lane = m
  {
    float s = 0.f, d = 0.f;
    int o0 = wv * 96;
    int swz[8];
#pragma unroll
    for (int j = 0; j < 8; ++j) swz[j] = (((lane >> 3) ^ j) << 3) + (lane & 7);
    for (int o8 = 0; o8 < 12; ++o8) {
#pragma unroll
      for (int j = 0; j < 8; ++j) {
        int o = o0 + o8 * 8 + j;
        float t = tanh_fast((float)Shp[o * 64 + swz[j]]);
        s += t * asrcL[o];
        d += t * adstL[o];
      }
    }
    redS[wv * 64 + lane] = s;
    redD[wv * 64 + lane] = d;
  }
  __syncthreads();
  if (tid < 64) {
    float s = 0.f, d = 0.f;
#pragma unroll
    for (int q = 0; q < 8; ++q) { s += redS[q * 64 + tid]; d += redD[q * 64 + tid]; }
    srcv[tid] = s;
    dstv[tid] = d;
  }
  __syncthreads();

  // softmax: wave wv rows 8*wv..+7, lane = neighbor m
#pragma unroll
  for (int r = 0; r < 8; ++r) {
    int n = wv * 8 + r;
    float logit = srcv[n] + dstv[lane];
    logit = logit >= 0.f ? logit : NEG_SLOPE * logit;
    bool ok = (maskRow[n] >> lane) & 1ULL;
    float v = ok ? logit : -1e30f;
    float mx = v;
#pragma unroll
    for (int off = 32; off > 0; off >>= 1) mx = fmaxf(mx, __shfl_xor(mx, off, 64));
    float e = ok ? __expf(v - mx) : 0.f;
    float sm = e;
#pragma unroll
    for (int off = 32; off > 0; off >>= 1) sm += __shfl_xor(sm, off, 64);
    attnL[n * 72 + lane] = (f16)(e / sm);
  }
  __syncthreads();

  // GEMM2: h1 = attn(64x64) @ hp(64x768) + bias; wave wv cols [wv*96, +96)
#pragma unroll
  for (int ctg = 0; ctg < 2; ++ctg) {
    int c0 = wv * 96 + ctg * 48;
    f32x4 acc[4][3];
#pragma unroll
    for (int rt = 0; rt < 4; ++rt)
#pragma unroll
      for (int ct = 0; ct < 3; ++ct)
        acc[rt][ct] = (f32x4){0.f, 0.f, 0.f, 0.f};
#pragma unroll
    for (int ks = 0; ks < 2; ++ks) {
      f16x8 af[4];
#pragma unroll
      for (int rt = 0; rt < 4; ++rt)
        af[rt] = *(const f16x8*)&attnL[(rt * 16 + l16) * 72 + ks * 32 + quad * 8];
#pragma unroll
      for (int ct = 0; ct < 3; ++ct) {
        int o = c0 + ct * 16 + l16;
        int m8 = ks * 4 + quad;   // (k-base)>>3
        f16x8 bf = *(const f16x8*)&Shp[o * 64 + ((m8 ^ (o & 7)) << 3)];
#pragma unroll
        for (int rt = 0; rt < 4; ++rt)
          acc[rt][ct] = __builtin_amdgcn_mfma_f32_16x16x32_f16(af[rt], bf, acc[rt][ct], 0, 0, 0);
      }
    }
#pragma unroll
    for (int rt = 0; rt < 4; ++rt)
#pragma unroll
      for (int ct = 0; ct < 3; ++ct) {
        int o = c0 + ct * 16 + l16;
        float bv = biasL[o];
#pragma unroll
        for (int i = 0; i < 4; ++i) {
          int n = rt * 16 + quad * 4 + i;
          h1[(size_t)b * HB + (size_t)n * DF + o] = (f16)(acc[rt][ct][i] + bv);
        }
      }
  }
}

// ---------- attention layer 2: only row 0 -> cneigh (l2-normed) ----------
__global__ __launch_bounds__(256) void attn_l2(
    const float* __restrict__ batch,
    const f16* __restrict__ hpT,      // [b][o][m] layer-2 hp
    const float* __restrict__ a_src,
    const float* __restrict__ a_dst,
    const float* __restrict__ gat_bias,
    f16* __restrict__ cneighW)
{
  __shared__ float asrcL[DF], adstL[DF], biasL[DF];
  __shared__ float redS[4 * NN], redD[4 * NN];
  __shared__ float dstv[NN], attn0[NN], h2row[DF], ssq[4];
  __shared__ float srcv0;
  __shared__ unsigned long long mask0;

  const int tid  = threadIdx.x;
  const int lane = tid & 63;
  const int wv   = tid >> 6;    // 0..3
  const int b    = blockIdx.x;
  const float* bb = batch + (size_t)b * (NN * DN);
  const f16* hp = hpT + (size_t)b * HB;

  for (int i = tid; i < DF; i += 256) {
    asrcL[i] = a_src[i];
    adstL[i] = a_dst[i];
    biasL[i] = gat_bias[i];
  }
  if (wv == 0) {
    float av = bb[DF + lane];   // row 0 adjacency
    unsigned long long m = __ballot(av != 0.0f);
    if (lane == 0) mask0 = m | 1ULL;
  }
  __syncthreads();

  // tanh dots: wave wv covers o in [wv*192, +192), lane = m (streaming global)
  {
    float s = 0.f, d = 0.f;
    int o0 = wv * 192;
    for (int oi = 0; oi < 192; ++oi) {
      int o = o0 + oi;
      float t = tanh_fast((float)hp[(size_t)o * 64 + lane]);
      s += t * asrcL[o];
      d += t * adstL[o];
    }
    redS[wv * 64 + lane] = s;
    redD[wv * 64 + lane] = d;
  }
  __syncthreads();
  if (tid < 64) {
    dstv[tid] = redD[tid] + redD[64 + tid] + redD[128 + tid] + redD[192 + tid];
    if (tid == 0) srcv0 = redS[0] + redS[64] + redS[128] + redS[192];
  }
  __syncthreads();
  if (wv == 0) {
    float logit = srcv0 + dstv[lane];
    logit = logit >= 0.f ? logit : NEG_SLOPE * logit;
    bool ok = (mask0 >> lane) & 1ULL;
    float v = ok ? logit : -1e30f;
    float mx = v;
#pragma unroll
    for (int off = 32; off > 0; off >>= 1) mx = fmaxf(mx, __shfl_xor(mx, off, 64));
    float e = ok ? __expf(v - mx) : 0.f;
    float sm = e;
#pragma unroll
    for (int off = 32; off > 0; off >>= 1) sm += __shfl_xor(sm, off, 64);
    attn0[lane] = e / sm;
  }
  __syncthreads();
  // h2row[o] = bias[o] + sum_m attn0[m] * hp[o][m]
  for (int o = tid; o < DF; o += 256) {
    const f16* rp = hp + (size_t)o * 64;
    float a = biasL[o];
#pragma unroll
    for (int j = 0; j < 8; ++j) {
      f16x8 v = *(const f16x8*)&rp[j * 8];
#pragma unroll
      for (int e = 0; e < 8; ++e) a += attn0[j * 8 + e] * (float)v[e];
    }
    h2row[o] = a;
  }
  __syncthreads();
  float p = 0.f;
  for (int o = tid; o < DF; o += 256) p += h2row[o] * h2row[o];
#pragma unroll
  for (int off = 32; off > 0; off >>= 1) p += __shfl_xor(p, off, 64);
  if (lane == 0) ssq[wv] = p;
  __syncthreads();
  if (tid == 0) {
    float ss = ssq[0] + ssq[1] + ssq[2] + ssq[3];
    ssq[0] = 1.0f / fmaxf(sqrtf(ss), 1e-12f);
  }
  __syncthreads();
  float scale = ssq[0];
  for (int o = tid; o < DF; o += 256)
    cneighW[(size_t)b * DF + o] = (f16)(h2row[o] * scale);
}

// ---------- final MLP GEMM (unchanged from R5) ----------
#define LDA 1540
__global__ __launch_bounds__(256) void final_mlp(
    const float* __restrict__ batch,
    const f16* __restrict__ cneighW,
    const f16* __restrict__ mwh,
    const float* __restrict__ mlp_b,
    float* __restrict__ out)
{
  __shared__ __align__(16) f16 Abuf[16 * LDA];
  const int tid  = threadIdx.x;
  const int lane = tid & 63;
  const int wv   = tid >> 6;
  const int l16  = lane & 15;
  const int quad = lane >> 4;
  const int b0   = blockIdx.x * 16;
  const int cb   = blockIdx.y * 128 + wv * 32;

  for (int i = tid; i < 16 * 384; i += 256) {
    int r = i / 384, c4 = i - r * 384;
    int j = c4 * 4;
    f16x4 h4;
    if (j < DF) {
      float4 v = *(const float4*)&batch[(size_t)(b0 + r) * (NN * DN) + j];
      h4 = (f16x4){(f16)v.x, (f16)v.y, (f16)v.z, (f16)v.w};
    } else {
      h4 = *(const f16x4*)&cneighW[(size_t)(b0 + r) * DF + (j - DF)];
    }
    *(f16x4*)&Abuf[r * LDA + j] = h4;
  }
  __syncthreads();

  f32x4 acc[2];
  acc[0] = (f32x4){0.f, 0.f, 0.f, 0.f};
  acc[1] = (f32x4){0.f, 0.f, 0.f, 0.f};

  const f16* mp = mwh + (size_t)(cb + l16) * (2 * DF) + quad * 8;
  f16x8 bfr[2], bnx[2];
  bfr[0] = *(const f16x8*)(mp);
  bfr[1] = *(const f16x8*)(mp + (size_t)16 * (2 * DF));

#pragma clang loop unroll(disable)
  for (int k0 = 0; k0 < 2 * DF; k0 += 32) {
    int kn = (k0 + 32 < 2 * DF) ? (k0 + 32) : 0;
    bnx[0] = *(const f16x8*)(mp + kn);
    bnx[1] = *(const f16x8*)(mp + (size_t)16 * (2 * DF) + kn);
    f16x4 a0 = *(const f16x4*)&Abuf[l16 * LDA + k0 + quad * 8];
    f16x4 a1 = *(const f16x4*)&Abuf[l16 * LDA + k0 + quad * 8 + 4];
    f16x8 af = {a0[0], a0[1], a0[2], a0[3], a1[0], a1[1], a1[2], a1[3]};
    acc[0] = __builtin_amdgcn_mfma_f32_16x16x32_f16(af, bfr[0], acc[0], 0, 0, 0);
    acc[1] = __builtin_amdgcn_mfma_f32_16x16x32_f16(af, bfr[1], acc[1], 0, 0, 0);
    bfr[0] = bnx[0];
    bfr[1] = bnx[1];
  }
#pragma unroll
  for (int ct = 0; ct < 2; ++ct) {
    int col = cb + ct * 16 + l16;
    float bv = mlp_b[col];
#pragma unroll
    for (int i = 0; i < 4; ++i) {
      int row = quad * 4 + i;
      out[(size_t)(b0 + row) * DF + col] = acc[ct][i] + bv;
    }
  }
}

__global__ __launch_bounds__(256) void l2norm_rows(float* __restrict__ out) {
  const int lane = threadIdx.x & 63;
  const int wv   = threadIdx.x >> 6;
  const int row  = blockIdx.x * 4 + wv;
  float* rp = out + (size_t)row * DF;
  float v[12];
  float ss = 0.f;
#pragma unroll
  for (int j = 0; j < 12; ++j) {
    v[j] = rp[j * 64 + lane];
    ss += v[j] * v[j];
  }
#pragma unroll
  for (int off = 32; off > 0; off >>= 1) ss += __shfl_xor(ss, off, 64);
  float sc = 1.0f / fmaxf(sqrtf(ss), 1e-12f);
#pragma unroll
  for (int j = 0; j < 12; ++j) rp[j * 64 + lane] = v[j] * sc;
}

extern "C" void kernel_launch(void* const* d_in, const int* in_sizes, int n_in,
                              void* d_out, int out_size, void* d_ws, size_t ws_size,
                              hipStream_t stream) {
  const float* batch    = (const float*)d_in[0];
  const float* w        = (const float*)d_in[1];
  const float* a_src    = (const float*)d_in[2];
  const float* a_dst    = (const float*)d_in[3];
  const float* gat_bias = (const float*)d_in[4];
  const float* mlp_w    = (const float*)d_in[5];
  const float* mlp_b    = (const float*)d_in[6];
  float* out = (float*)d_out;

  // workspace (f16): wT | mwh | cneigh | hA (hpT) | hB (h1)  ~= 105 MB
  f16* wT      = (f16*)d_ws;
  f16* mwh     = wT + (size_t)DF * DF;
  f16* cneighW = mwh + (size_t)DF * 2 * DF;
  f16* hA      = cneighW + (size_t)512 * DF;
  f16* hB      = hA + (size_t)512 * HB;

  prep_wT<<<dim3(24 * 24), dim3(256), 0, stream>>>(w, wT);
  prep_mlp<<<dim3((DF * 2 * DF) / 256), dim3(256), 0, stream>>>(mlp_w, mwh);
  // layer 1
  gemm_hp<<<dim3(256, 6), dim3(256), 0, stream>>>(batch, hB, wT, hA, 1);
  attn_l1<<<dim3(512), dim3(512), 0, stream>>>(batch, hA, a_src, a_dst, gat_bias, hB);
  // layer 2
  gemm_hp<<<dim3(256, 6), dim3(256), 0, stream>>>(batch, hB, wT, hA, 0);
  attn_l2<<<dim3(512), dim3(256), 0, stream>>>(batch, hA, a_src, a_dst, gat_bias, cneighW);
  // MLP + row l2norm
  final_mlp<<<dim3(32, 6), dim3(256), 0, stream>>>(batch, cneighW, mwh, mlp_b, out);
  l2norm_rows<<<dim3(128), dim3(256), 0, stream>>>(out);
}